// Round 3
// baseline (156.421 us; speedup 1.0000x reference)
//
#include <hip/hip_runtime.h>
#include <hip/hip_bf16.h>

// BallQueryAttention on MI355X (gfx950).
// out_i = (S_ball_i + K*(S_tot - S_ball_i)) / (c_i + K*(N - c_i)),  K = exp(-1)
// d2 = sq_i + sq_j - 2*dot;  dot via split-bf16 MFMA (hi*hi + hi*lo + lo*hi).
// Swapped dot (A=x_j, B=x_i) puts mask bits in A-fragment layout for the
// S-MFMA via a k-permutation baked into the transposed LDS tile (jslot).
// Counts via popcount of the packed mask words (7 set bits per member).

#define NROWS 8192
#define DDIM  64

typedef __bf16 bf16x8 __attribute__((ext_vector_type(8)));
typedef float  f32x4  __attribute__((ext_vector_type(4)));
typedef unsigned int u32;
typedef u32 u32x4 __attribute__((ext_vector_type(4)));

#define MFMA16(A, B, C) __builtin_amdgcn_mfma_f32_16x16x32_bf16((A), (B), (C), 0, 0, 0)

static __device__ __forceinline__ unsigned short bf16rn(float f) {
    unsigned u = __float_as_uint(f);
    unsigned r = u + 0x7FFFu + ((u >> 16) & 1u);
    return (unsigned short)(r >> 16);
}
static __device__ __forceinline__ float bf16tof(unsigned short h) {
    return __uint_as_float(((unsigned)h) << 16);
}

// ---------------- prep: hi/lo split + row sq-norms + column totals ---------
__global__ __launch_bounds__(256) void prep(const float* __restrict__ x,
                                            unsigned short* __restrict__ xhi,
                                            unsigned short* __restrict__ xlo,
                                            float* __restrict__ sq,
                                            float* __restrict__ stot) {
    __shared__ float sp[4][64];
    int t = blockIdx.x * 256 + threadIdx.x;   // thread = (row, 4-col group)
    int row = t >> 4, q = t & 15;
    const float4 v = *(const float4*)(x + ((size_t)row << 6) + (q << 2));
    float f0 = v.x, f1 = v.y, f2 = v.z, f3 = v.w;
    unsigned short h0 = bf16rn(f0), h1 = bf16rn(f1), h2 = bf16rn(f2), h3 = bf16rn(f3);
    unsigned short l0 = bf16rn(f0 - bf16tof(h0));
    unsigned short l1 = bf16rn(f1 - bf16tof(h1));
    unsigned short l2 = bf16rn(f2 - bf16tof(h2));
    unsigned short l3 = bf16rn(f3 - bf16tof(h3));
    uint2 ph, pl;
    ph.x = (u32)h0 | ((u32)h1 << 16);  ph.y = (u32)h2 | ((u32)h3 << 16);
    pl.x = (u32)l0 | ((u32)l1 << 16);  pl.y = (u32)l2 | ((u32)l3 << 16);
    *(uint2*)(xhi + ((size_t)row << 6) + (q << 2)) = ph;
    *(uint2*)(xlo + ((size_t)row << 6) + (q << 2)) = pl;
    // row sq-norm: reduce over 16 lanes sharing the row
    float ss = f0 * f0;
    ss = fmaf(f1, f1, ss); ss = fmaf(f2, f2, ss); ss = fmaf(f3, f3, ss);
    ss += __shfl_xor(ss, 1); ss += __shfl_xor(ss, 2);
    ss += __shfl_xor(ss, 4); ss += __shfl_xor(ss, 8);
    if (q == 0) sq[row] = ss;
    // column totals: sum this block's 16 rows, one atomic per col per block
    f0 += __shfl_xor(f0, 16); f0 += __shfl_xor(f0, 32);
    f1 += __shfl_xor(f1, 16); f1 += __shfl_xor(f1, 32);
    f2 += __shfl_xor(f2, 16); f2 += __shfl_xor(f2, 32);
    f3 += __shfl_xor(f3, 16); f3 += __shfl_xor(f3, 32);
    int l = threadIdx.x & 63, wv = threadIdx.x >> 6;
    if (l < 16) {
        sp[wv][l * 4 + 0] = f0; sp[wv][l * 4 + 1] = f1;
        sp[wv][l * 4 + 2] = f2; sp[wv][l * 4 + 3] = f3;
    }
    __syncthreads();
    if (threadIdx.x < 64) {
        float s = sp[0][threadIdx.x] + sp[1][threadIdx.x] +
                  sp[2][threadIdx.x] + sp[3][threadIdx.x];
        atomicAdd(stot + threadIdx.x, s);
    }
}

// k-permutation: physical j (0..63 in tile) -> k slot
static __device__ __forceinline__ int jslot(int j) {
    return (j & 32) | (((j >> 2) & 3) << 3) | (((j >> 4) & 1) << 2) | (j & 3);
}
// XOR-swizzled LDS address for the transposed tile (row stride 160 B)
static __device__ __forceinline__ char* jt_addr(char* base, int d, int bytecol) {
    return base + d * 160 + (bytecol ^ ((d & 7) << 4));
}

// ---------------- main fused kernel ---------------------------------------
// grid = 64 i-tiles (BI=128) x 12 chunks (variable 10/11 j-tiles of 64).
// 256 threads = 4 waves, each owning 32 i-rows.
__global__ __launch_bounds__(256, 3) void ballq_main(
        const unsigned short* __restrict__ xhi,
        const unsigned short* __restrict__ xlo,
        const float* __restrict__ sq,
        float* __restrict__ S, float* __restrict__ cnt) {
    __shared__ char sJT[2][64 * 160];         // [buf][d][jslot] bf16, swizzled
    __shared__ float sqJ[2][64];

    const int tid = threadIdx.x;
    const int w = tid >> 6, l = tid & 63, l16 = l & 15, lg = l >> 4;
    const int itile = blockIdx.x & 63, chunk = blockIdx.x >> 6;   // chunk 0..11
    const int i0 = (itile << 7) + w * 32;     // wave's 32 rows
    const int jt0 = chunk * 10 + (chunk < 8 ? chunk : 8);
    const int jtn = (chunk < 8) ? 11 : 10;    // 8*11 + 4*10 = 128 tiles

    // hoisted i-fragments (B operand) + sq_i
    bf16x8 ihi[2][2], ilo[2][2];
    float sqi[2];
#pragma unroll
    for (int mt = 0; mt < 2; ++mt) {
        int ir = i0 + mt * 16 + l16;
#pragma unroll
        for (int ks = 0; ks < 2; ++ks) {
            size_t off = (size_t)ir * 64 + ks * 32 + lg * 8;
            ihi[mt][ks] = *(const bf16x8*)(xhi + off);
            ilo[mt][ks] = *(const bf16x8*)(xlo + off);
        }
        sqi[mt] = sq[ir];
    }

    f32x4 accS[2][4];
    u32 pcnt[2] = {0u, 0u};                   // popcount accumulators
#pragma unroll
    for (int a = 0; a < 2; ++a)
#pragma unroll
        for (int b = 0; b < 4; ++b) {
            accS[a][b][0] = 0.f; accS[a][b][1] = 0.f;
            accS[a][b][2] = 0.f; accS[a][b][3] = 0.f;
        }

    const int sj = (tid & 31) * 2;            // staging: row pair (even)
    const int sd0 = (tid >> 5) * 8;           // staging: d block
    const int sslot = jslot(sj);              // even -> u32-aligned

    // prologue: stage tile jt0 into buf 0
    {
        int j0 = jt0 << 6;
        uint4 h0 = *(const uint4*)(xhi + (size_t)(j0 + sj) * 64 + sd0);
        uint4 h1 = *(const uint4*)(xhi + (size_t)(j0 + sj + 1) * 64 + sd0);
        float sqv = (tid < 64) ? sq[j0 + tid] : 0.f;
        const unsigned short* a0 = (const unsigned short*)&h0;
        const unsigned short* a1 = (const unsigned short*)&h1;
#pragma unroll
        for (int e = 0; e < 8; ++e) {
            u32 pv = (u32)a0[e] | ((u32)a1[e] << 16);
            *(u32*)jt_addr(sJT[0], sd0 + e, sslot * 2) = pv;
        }
        if (tid < 64) sqJ[0][tid] = sqv;
    }
    __syncthreads();

    int buf = 0;
    for (int t = 0; t < jtn; ++t) {
        const int j0 = (jt0 + t) << 6;
        const bool more = (t + 1 < jtn);
        uint4 n0, n1; float nsq = 0.f;
        if (more) {                            // issue next-tile loads early
            int jn = j0 + 64;
            n0 = *(const uint4*)(xhi + (size_t)(jn + sj) * 64 + sd0);
            n1 = *(const uint4*)(xhi + (size_t)(jn + sj + 1) * 64 + sd0);
            if (tid < 64) nsq = sq[jn + tid];
        }

        // ---- dot phase: A = x_j (global, L2-hot), B = hoisted x_i ----
        f32x4 accD[4][2];
#pragma unroll
        for (int a = 0; a < 4; ++a)
#pragma unroll
            for (int b = 0; b < 2; ++b) {
                accD[a][b][0] = 0.f; accD[a][b][1] = 0.f;
                accD[a][b][2] = 0.f; accD[a][b][3] = 0.f;
            }
#pragma unroll
        for (int nt = 0; nt < 4; ++nt) {
            bf16x8 jh[2], jl[2];
#pragma unroll
            for (int ks = 0; ks < 2; ++ks) {
                size_t off = (size_t)(j0 + nt * 16 + l16) * 64 + ks * 32 + lg * 8;
                jh[ks] = *(const bf16x8*)(xhi + off);
                jl[ks] = *(const bf16x8*)(xlo + off);
            }
#pragma unroll
            for (int mt = 0; mt < 2; ++mt)
#pragma unroll
                for (int ks = 0; ks < 2; ++ks) {
                    accD[nt][mt] = MFMA16(jh[ks], ihi[mt][ks], accD[nt][mt]);
                    accD[nt][mt] = MFMA16(jh[ks], ilo[mt][ks], accD[nt][mt]);
                    accD[nt][mt] = MFMA16(jl[ks], ihi[mt][ks], accD[nt][mt]);
                }
        }

        // ---- threshold -> mask bits packed straight into A-fragments ----
        u32 Fw[2][8];                          // [mt][kj*4 + word]
#pragma unroll
        for (int nt = 0; nt < 4; ++nt) {
            const int kj = nt >> 1, s = nt & 1;
            float sqr0 = sqJ[buf][nt * 16 + lg * 4 + 0];
            float sqr1 = sqJ[buf][nt * 16 + lg * 4 + 1];
            float sqr2 = sqJ[buf][nt * 16 + lg * 4 + 2];
            float sqr3 = sqJ[buf][nt * 16 + lg * 4 + 3];
#pragma unroll
            for (int mt = 0; mt < 2; ++mt) {
                float base = sqi[mt];
                bool in0 = fmaf(-2.f, accD[nt][mt][0], base + sqr0) <= 121.f;
                bool in1 = fmaf(-2.f, accD[nt][mt][1], base + sqr1) <= 121.f;
                bool in2 = fmaf(-2.f, accD[nt][mt][2], base + sqr2) <= 121.f;
                bool in3 = fmaf(-2.f, accD[nt][mt][3], base + sqr3) <= 121.f;
                Fw[mt][kj * 4 + s * 2 + 0] =
                    (in0 ? 0x3F80u : 0u) | (in1 ? 0x3F800000u : 0u);
                Fw[mt][kj * 4 + s * 2 + 1] =
                    (in2 ? 0x3F80u : 0u) | (in3 ? 0x3F800000u : 0u);
            }
        }
        // counts: each member contributes 7 set bits (0x3F80 / 0x3F800000)
#pragma unroll
        for (int mt = 0; mt < 2; ++mt)
#pragma unroll
            for (int wd = 0; wd < 8; ++wd)
                pcnt[mt] += (u32)__builtin_popcount(Fw[mt][wd]);

        // ---- S phase: S_ball += mask @ Xhi (B from permuted sJT) ----
#pragma unroll
        for (int kj = 0; kj < 2; ++kj) {
            u32x4 fa0 = {Fw[0][kj * 4 + 0], Fw[0][kj * 4 + 1],
                         Fw[0][kj * 4 + 2], Fw[0][kj * 4 + 3]};
            u32x4 fa1 = {Fw[1][kj * 4 + 0], Fw[1][kj * 4 + 1],
                         Fw[1][kj * 4 + 2], Fw[1][kj * 4 + 3]};
            bf16x8 m0 = __builtin_bit_cast(bf16x8, fa0);
            bf16x8 m1 = __builtin_bit_cast(bf16x8, fa1);
#pragma unroll
            for (int ntd = 0; ntd < 4; ++ntd) {
                const bf16x8* bp = (const bf16x8*)__builtin_assume_aligned(
                    jt_addr(sJT[buf], ntd * 16 + l16, kj * 64 + lg * 16), 16);
                bf16x8 bT = *bp;
                accS[0][ntd] = MFMA16(m0, bT, accS[0][ntd]);
                accS[1][ntd] = MFMA16(m1, bT, accS[1][ntd]);
            }
        }

        // ---- write next-tile staging into other buffer ----
        if (more) {
            const unsigned short* a0 = (const unsigned short*)&n0;
            const unsigned short* a1 = (const unsigned short*)&n1;
#pragma unroll
            for (int e = 0; e < 8; ++e) {
                u32 pv = (u32)a0[e] | ((u32)a1[e] << 16);
                *(u32*)jt_addr(sJT[buf ^ 1], sd0 + e, sslot * 2) = pv;
            }
            if (tid < 64) sqJ[buf ^ 1][tid] = nsq;
        }
        __syncthreads();
        buf ^= 1;
    }

    // ---- epilogue: per-wave-exclusive rows, atomics into L2 buffers ----
#pragma unroll
    for (int mt = 0; mt < 2; ++mt) {
        u32 v = pcnt[mt];
        v += __shfl_xor(v, 16);
        v += __shfl_xor(v, 32);
        if (lg == 0) atomicAdd(cnt + i0 + mt * 16 + l16, (float)(v / 7u));
    }
#pragma unroll
    for (int mt = 0; mt < 2; ++mt)
#pragma unroll
        for (int ntd = 0; ntd < 4; ++ntd)
#pragma unroll
            for (int r = 0; r < 4; ++r) {
                size_t idx = (size_t)(i0 + mt * 16 + lg * 4 + r) * 64 + ntd * 16 + l16;
                atomicAdd(S + idx, accS[mt][ntd][r]);
            }
}

// ---------------- combine ---------------------------------------------------
__global__ __launch_bounds__(256) void ballq_combine(
        const float* __restrict__ S, const float* __restrict__ cnt,
        const float* __restrict__ stot, float* __restrict__ out) {
    int t = blockIdx.x * 256 + threadIdx.x;   // 131072 threads x float4
    int i = t >> 4, d0 = (t & 15) << 2;
    float c = cnt[i];
    f32x4 s = *(const f32x4*)(S + (size_t)i * 64 + d0);
    f32x4 st = *(const f32x4*)(stot + d0);
    const float K = 0.36787944117144233f;     // exp(-1)
    float den = 1.f / (c + K * (8192.f - c));
    f32x4 o;
#pragma unroll
    for (int k = 0; k < 4; ++k) o[k] = (s[k] + K * (st[k] - s[k])) * den;
    *(f32x4*)(out + (size_t)i * 64 + d0) = o;
}

extern "C" void kernel_launch(void* const* d_in, const int* in_sizes, int n_in,
                              void* d_out, int out_size, void* d_ws, size_t ws_size,
                              hipStream_t stream) {
    (void)in_sizes; (void)n_in; (void)out_size; (void)ws_size;
    const float* x = (const float*)d_in[0];
    float* out = (float*)d_out;
    char* ws = (char*)d_ws;

    unsigned short* xhi = (unsigned short*)ws;                  // 1 MB
    unsigned short* xlo = (unsigned short*)(ws + (1u << 20));   // 1 MB
    float* sq   = (float*)(ws + (2u << 20));                    // 32 KB
    float* S    = (float*)(ws + (2u << 20) + 32768);            // 2 MB
    float* cnt  = (float*)(ws + (2u << 20) + 32768 + (1u << 21));      // 32 KB
    float* stot = (float*)(ws + (2u << 20) + 32768 + (1u << 21) + 32768); // 256 B

    // zero S + cnt + stot (contiguous)
    hipMemsetAsync(S, 0, (1u << 21) + 32768 + 256, stream);
    prep<<<512, 256, 0, stream>>>(x, xhi, xlo, sq, stot);
    ballq_main<<<64 * 12, 256, 0, stream>>>(xhi, xlo, sq, S, cnt);
    ballq_combine<<<512, 256, 0, stream>>>(S, cnt, stot, out);
}

// Round 4
// 119.420 us; speedup vs baseline: 1.3098x; 1.3098x over previous
//
#include <hip/hip_runtime.h>
#include <hip/hip_bf16.h>

// BallQueryAttention on MI355X (gfx950).
// out_i = (S_ball_i + K*(S_tot - S_ball_i)) / (c_i + K*(N - c_i)),  K = exp(-1)
// d2 = sq_i + sq_j - 2*dot;  dot via split-bf16 MFMA (hi*hi + hi*lo + lo*hi).
// Swapped dot (A=x_j, B=x_i) puts mask bits in A-fragment layout for the
// S-MFMA via a k-permutation baked into the transposed LDS tile (jslot).
// x_j tiles staged to LDS via global_load_lds (16B) with both-sides XOR
// chunk swizzle (linear LDS dest, pre-swizzled global source, swizzled read).

#define NROWS 8192

typedef __bf16 bf16x8 __attribute__((ext_vector_type(8)));
typedef float  f32x4  __attribute__((ext_vector_type(4)));
typedef unsigned int u32;
typedef u32 u32x4 __attribute__((ext_vector_type(4)));

#define MFMA16(A, B, C) __builtin_amdgcn_mfma_f32_16x16x32_bf16((A), (B), (C), 0, 0, 0)

#define GLOAD16(g, l)                                                     \
    __builtin_amdgcn_global_load_lds(                                     \
        (const __attribute__((address_space(1))) u32*)(g),                \
        (__attribute__((address_space(3))) u32*)(l), 16, 0, 0)

static __device__ __forceinline__ unsigned short bf16rn(float f) {
    unsigned u = __float_as_uint(f);
    unsigned r = u + 0x7FFFu + ((u >> 16) & 1u);
    return (unsigned short)(r >> 16);
}
static __device__ __forceinline__ float bf16tof(unsigned short h) {
    return __uint_as_float(((unsigned)h) << 16);
}

// ---------------- prep: hi/lo split + row sq-norms + column totals ---------
__global__ __launch_bounds__(256) void prep(const float* __restrict__ x,
                                            unsigned short* __restrict__ xhi,
                                            unsigned short* __restrict__ xlo,
                                            float* __restrict__ sq,
                                            float* __restrict__ stot) {
    __shared__ float sp[4][64];
    int t = blockIdx.x * 256 + threadIdx.x;   // thread = (row, 4-col group)
    int row = t >> 4, q = t & 15;
    const float4 v = *(const float4*)(x + ((size_t)row << 6) + (q << 2));
    float f0 = v.x, f1 = v.y, f2 = v.z, f3 = v.w;
    unsigned short h0 = bf16rn(f0), h1 = bf16rn(f1), h2 = bf16rn(f2), h3 = bf16rn(f3);
    unsigned short l0 = bf16rn(f0 - bf16tof(h0));
    unsigned short l1 = bf16rn(f1 - bf16tof(h1));
    unsigned short l2 = bf16rn(f2 - bf16tof(h2));
    unsigned short l3 = bf16rn(f3 - bf16tof(h3));
    uint2 ph, pl;
    ph.x = (u32)h0 | ((u32)h1 << 16);  ph.y = (u32)h2 | ((u32)h3 << 16);
    pl.x = (u32)l0 | ((u32)l1 << 16);  pl.y = (u32)l2 | ((u32)l3 << 16);
    *(uint2*)(xhi + ((size_t)row << 6) + (q << 2)) = ph;
    *(uint2*)(xlo + ((size_t)row << 6) + (q << 2)) = pl;
    float ss = f0 * f0;
    ss = fmaf(f1, f1, ss); ss = fmaf(f2, f2, ss); ss = fmaf(f3, f3, ss);
    ss += __shfl_xor(ss, 1); ss += __shfl_xor(ss, 2);
    ss += __shfl_xor(ss, 4); ss += __shfl_xor(ss, 8);
    if (q == 0) sq[row] = ss;
    f0 += __shfl_xor(f0, 16); f0 += __shfl_xor(f0, 32);
    f1 += __shfl_xor(f1, 16); f1 += __shfl_xor(f1, 32);
    f2 += __shfl_xor(f2, 16); f2 += __shfl_xor(f2, 32);
    f3 += __shfl_xor(f3, 16); f3 += __shfl_xor(f3, 32);
    int l = threadIdx.x & 63, wv = threadIdx.x >> 6;
    if (l < 16) {
        sp[wv][l * 4 + 0] = f0; sp[wv][l * 4 + 1] = f1;
        sp[wv][l * 4 + 2] = f2; sp[wv][l * 4 + 3] = f3;
    }
    __syncthreads();
    if (threadIdx.x < 64) {
        float s = sp[0][threadIdx.x] + sp[1][threadIdx.x] +
                  sp[2][threadIdx.x] + sp[3][threadIdx.x];
        atomicAdd(stot + threadIdx.x, s);
    }
}

// k-permutation: physical j (0..63 in tile) -> k slot
static __device__ __forceinline__ int jslot(int j) {
    return (j & 32) | (((j >> 2) & 3) << 3) | (((j >> 4) & 1) << 2) | (j & 3);
}

// ---------------- main fused kernel ---------------------------------------
// grid = 64 i-tiles (BI=128) x 12 chunks (8x11 + 4x10 j-tiles of 64).
// 256 threads = 4 waves, each owning 32 i-rows. 3 blocks/CU.
__global__ __launch_bounds__(256, 3) void ballq_main(
        const unsigned short* __restrict__ xhi,
        const unsigned short* __restrict__ xlo,
        const float* __restrict__ sq,
        float* __restrict__ S, float* __restrict__ cnt) {
    __shared__ char sHI[2][8192];             // [buf][j][d] bf16 hi, chunk-swz
    __shared__ char sLO[2][8192];             // [buf][j][d] bf16 lo, chunk-swz
    __shared__ char sJT[2][8192];             // [buf][d][jslot] bf16, XOR-swz
    __shared__ float sqJ[2][64];

    const int tid = threadIdx.x;
    const int w = tid >> 6, l = tid & 63, l16 = l & 15, lg = l >> 4;
    const int itile = blockIdx.x & 63, chunk = blockIdx.x >> 6;   // chunk 0..11
    const int i0 = (itile << 7) + w * 32;     // wave's 32 rows
    const int jt0 = chunk * 10 + (chunk < 8 ? chunk : 8);
    const int jtn = (chunk < 8) ? 11 : 10;    // 8*11 + 4*10 = 128 tiles

    // global_load_lds staging lane constants: lane l covers row (base + l>>3),
    // lds chunk l&7; source chunk pre-swizzled so read-side XOR matches.
    const int srow = l >> 3;
    const int schunk = (l & 7) ^ srow;        // involution: c_lds ^ (row&7)
    const size_t gsoff = ((size_t)srow << 6) + (schunk << 3);  // shorts

    // sJT reg staging (transposed scatter)
    const int sj = (tid & 31) * 2;            // even j pair
    const int sd0 = (tid >> 5) * 8;           // d block
    const int sslot2 = jslot(sj) * 2;         // byte col, u32-aligned

    // hoisted i-fragments (B operand) + sq_i
    bf16x8 ihi[2][2], ilo[2][2];
    float sqi[2];
#pragma unroll
    for (int mt = 0; mt < 2; ++mt) {
        int ir = i0 + mt * 16 + l16;
#pragma unroll
        for (int ks = 0; ks < 2; ++ks) {
            size_t off = (size_t)ir * 64 + ks * 32 + lg * 8;
            ihi[mt][ks] = *(const bf16x8*)(xhi + off);
            ilo[mt][ks] = *(const bf16x8*)(xlo + off);
        }
        sqi[mt] = sq[ir];
    }

    f32x4 accS[2][4];
    u32 pcnt[2] = {0u, 0u};
#pragma unroll
    for (int a = 0; a < 2; ++a)
#pragma unroll
        for (int b = 0; b < 4; ++b) {
            accS[a][b][0] = 0.f; accS[a][b][1] = 0.f;
            accS[a][b][2] = 0.f; accS[a][b][3] = 0.f;
        }

    // prologue: stage tile jt0 into buf 0
    {
        int j0 = jt0 << 6;
        const unsigned short* gh = xhi + ((size_t)(j0 + w * 16) << 6) + gsoff;
        const unsigned short* gl = xlo + ((size_t)(j0 + w * 16) << 6) + gsoff;
        GLOAD16(gh,       &sHI[0][w * 16 * 128]);
        GLOAD16(gh + 512, &sHI[0][(w * 16 + 8) * 128]);
        GLOAD16(gl,       &sLO[0][w * 16 * 128]);
        GLOAD16(gl + 512, &sLO[0][(w * 16 + 8) * 128]);
        uint4 h0 = *(const uint4*)(xhi + (size_t)(j0 + sj) * 64 + sd0);
        uint4 h1 = *(const uint4*)(xhi + (size_t)(j0 + sj + 1) * 64 + sd0);
        float sqv = (tid < 64) ? sq[j0 + tid] : 0.f;
        const unsigned short* a0 = (const unsigned short*)&h0;
        const unsigned short* a1 = (const unsigned short*)&h1;
#pragma unroll
        for (int e = 0; e < 8; ++e) {
            u32 pv = (u32)a0[e] | ((u32)a1[e] << 16);
            *(u32*)(sJT[0] + (sd0 + e) * 128 + (sslot2 ^ (e << 4))) = pv;
        }
        if (tid < 64) sqJ[0][tid] = sqv;
    }
    __syncthreads();

    const int csw = (lg ^ (l16 & 7)) << 4;    // read-side chunk swizzle (ks=0)
    int buf = 0;
    for (int t = 0; t < jtn; ++t) {
        const bool more = (t + 1 < jtn);
        uint4 n0, n1; float nsq = 0.f;
        if (more) {                            // issue ALL next-tile loads now
            int jn = (jt0 + t + 1) << 6;
            const unsigned short* gh = xhi + ((size_t)(jn + w * 16) << 6) + gsoff;
            const unsigned short* gl = xlo + ((size_t)(jn + w * 16) << 6) + gsoff;
            char* hb = sHI[buf ^ 1];
            char* lb = sLO[buf ^ 1];
            GLOAD16(gh,       hb + w * 16 * 128);
            GLOAD16(gh + 512, hb + (w * 16 + 8) * 128);
            GLOAD16(gl,       lb + w * 16 * 128);
            GLOAD16(gl + 512, lb + (w * 16 + 8) * 128);
            n0 = *(const uint4*)(xhi + (size_t)(jn + sj) * 64 + sd0);
            n1 = *(const uint4*)(xhi + (size_t)(jn + sj + 1) * 64 + sd0);
            if (tid < 64) nsq = sq[jn + tid];
        }

        // ---- dot phase: A = x_j (LDS, swizzled), B = hoisted x_i ----
        const char* hb = sHI[buf];
        const char* lb = sLO[buf];
        f32x4 accD[4][2];
#pragma unroll
        for (int a = 0; a < 4; ++a)
#pragma unroll
            for (int b = 0; b < 2; ++b) {
                accD[a][b][0] = 0.f; accD[a][b][1] = 0.f;
                accD[a][b][2] = 0.f; accD[a][b][3] = 0.f;
            }
#pragma unroll
        for (int nt = 0; nt < 4; ++nt) {
            const int ro = (nt * 16 + l16) * 128;
            bf16x8 jh[2], jl[2];
            jh[0] = *(const bf16x8*)(hb + ro + csw);
            jh[1] = *(const bf16x8*)(hb + ro + (csw ^ 64));
            jl[0] = *(const bf16x8*)(lb + ro + csw);
            jl[1] = *(const bf16x8*)(lb + ro + (csw ^ 64));
#pragma unroll
            for (int mt = 0; mt < 2; ++mt)
#pragma unroll
                for (int ks = 0; ks < 2; ++ks) {
                    accD[nt][mt] = MFMA16(jh[ks], ihi[mt][ks], accD[nt][mt]);
                    accD[nt][mt] = MFMA16(jh[ks], ilo[mt][ks], accD[nt][mt]);
                    accD[nt][mt] = MFMA16(jl[ks], ihi[mt][ks], accD[nt][mt]);
                }
        }

        // ---- threshold -> mask bits packed straight into A-fragments ----
        u32 Fw[2][8];                          // [mt][kj*4 + word]
#pragma unroll
        for (int nt = 0; nt < 4; ++nt) {
            const int kj = nt >> 1, s = nt & 1;
            f32x4 sqr = *(const f32x4*)&sqJ[buf][nt * 16 + lg * 4];
#pragma unroll
            for (int mt = 0; mt < 2; ++mt) {
                float base = sqi[mt];
                bool in0 = fmaf(-2.f, accD[nt][mt][0], base + sqr[0]) <= 121.f;
                bool in1 = fmaf(-2.f, accD[nt][mt][1], base + sqr[1]) <= 121.f;
                bool in2 = fmaf(-2.f, accD[nt][mt][2], base + sqr[2]) <= 121.f;
                bool in3 = fmaf(-2.f, accD[nt][mt][3], base + sqr[3]) <= 121.f;
                Fw[mt][kj * 4 + s * 2 + 0] =
                    (in0 ? 0x3F80u : 0u) | (in1 ? 0x3F800000u : 0u);
                Fw[mt][kj * 4 + s * 2 + 1] =
                    (in2 ? 0x3F80u : 0u) | (in3 ? 0x3F800000u : 0u);
            }
        }
#pragma unroll
        for (int mt = 0; mt < 2; ++mt)
#pragma unroll
            for (int wd = 0; wd < 8; ++wd)
                pcnt[mt] += (u32)__builtin_popcount(Fw[mt][wd]);

        // ---- S phase: S_ball += mask @ Xhi (B from permuted sJT) ----
#pragma unroll
        for (int kj = 0; kj < 2; ++kj) {
            u32x4 fa0 = {Fw[0][kj * 4 + 0], Fw[0][kj * 4 + 1],
                         Fw[0][kj * 4 + 2], Fw[0][kj * 4 + 3]};
            u32x4 fa1 = {Fw[1][kj * 4 + 0], Fw[1][kj * 4 + 1],
                         Fw[1][kj * 4 + 2], Fw[1][kj * 4 + 3]};
            bf16x8 m0 = __builtin_bit_cast(bf16x8, fa0);
            bf16x8 m1 = __builtin_bit_cast(bf16x8, fa1);
#pragma unroll
            for (int ntd = 0; ntd < 4; ++ntd) {
                const char* bp = sJT[buf] + (ntd * 16 + l16) * 128 +
                                 ((kj * 64 + lg * 16) ^ ((l16 & 7) << 4));
                bf16x8 bT = *(const bf16x8*)bp;
                accS[0][ntd] = MFMA16(m0, bT, accS[0][ntd]);
                accS[1][ntd] = MFMA16(m1, bT, accS[1][ntd]);
            }
        }

        // ---- write next-tile sJT staging into other buffer ----
        if (more) {
            char* jb = sJT[buf ^ 1];
            const unsigned short* a0 = (const unsigned short*)&n0;
            const unsigned short* a1 = (const unsigned short*)&n1;
#pragma unroll
            for (int e = 0; e < 8; ++e) {
                u32 pv = (u32)a0[e] | ((u32)a1[e] << 16);
                *(u32*)(jb + (sd0 + e) * 128 + (sslot2 ^ (e << 4))) = pv;
            }
            if (tid < 64) sqJ[buf ^ 1][tid] = nsq;
        }
        __syncthreads();                       // drains vmcnt: gloads landed
        buf ^= 1;
    }

    // ---- epilogue: per-wave-exclusive rows, atomics into L2 buffers ----
#pragma unroll
    for (int mt = 0; mt < 2; ++mt) {
        u32 v = pcnt[mt];
        v += __shfl_xor(v, 16);
        v += __shfl_xor(v, 32);
        if (lg == 0) atomicAdd(cnt + i0 + mt * 16 + l16, (float)(v / 7u));
    }
#pragma unroll
    for (int mt = 0; mt < 2; ++mt)
#pragma unroll
        for (int ntd = 0; ntd < 4; ++ntd)
#pragma unroll
            for (int r = 0; r < 4; ++r) {
                size_t idx = (size_t)(i0 + mt * 16 + lg * 4 + r) * 64 + ntd * 16 + l16;
                atomicAdd(S + idx, accS[mt][ntd][r]);
            }
}

// ---------------- combine ---------------------------------------------------
__global__ __launch_bounds__(256) void ballq_combine(
        const float* __restrict__ S, const float* __restrict__ cnt,
        const float* __restrict__ stot, float* __restrict__ out) {
    int t = blockIdx.x * 256 + threadIdx.x;   // 131072 threads x float4
    int i = t >> 4, d0 = (t & 15) << 2;
    float c = cnt[i];
    f32x4 s = *(const f32x4*)(S + (size_t)i * 64 + d0);
    f32x4 st = *(const f32x4*)(stot + d0);
    const float K = 0.36787944117144233f;     // exp(-1)
    float den = 1.f / (c + K * (8192.f - c));
    f32x4 o;
#pragma unroll
    for (int k = 0; k < 4; ++k) o[k] = (s[k] + K * (st[k] - s[k])) * den;
    *(f32x4*)(out + (size_t)i * 64 + d0) = o;
}

extern "C" void kernel_launch(void* const* d_in, const int* in_sizes, int n_in,
                              void* d_out, int out_size, void* d_ws, size_t ws_size,
                              hipStream_t stream) {
    (void)in_sizes; (void)n_in; (void)out_size; (void)ws_size;
    const float* x = (const float*)d_in[0];
    float* out = (float*)d_out;
    char* ws = (char*)d_ws;

    unsigned short* xhi = (unsigned short*)ws;                  // 1 MB
    unsigned short* xlo = (unsigned short*)(ws + (1u << 20));   // 1 MB
    float* sq   = (float*)(ws + (2u << 20));                    // 32 KB
    float* S    = (float*)(ws + (2u << 20) + 32768);            // 2 MB
    float* cnt  = (float*)(ws + (2u << 20) + 32768 + (1u << 21));      // 32 KB
    float* stot = (float*)(ws + (2u << 20) + 32768 + (1u << 21) + 32768); // 256 B

    hipMemsetAsync(S, 0, (1u << 21) + 32768 + 256, stream);
    prep<<<512, 256, 0, stream>>>(x, xhi, xlo, sq, stot);
    ballq_main<<<64 * 12, 256, 0, stream>>>(xhi, xlo, sq, S, cnt);
    ballq_combine<<<512, 256, 0, stream>>>(S, cnt, stot, out);
}